// Round 9
// baseline (38566.153 us; speedup 1.0000x reference)
//
#include <hip/hip_runtime.h>
#include <stdint.h>

#define N 2048
#define BATCH 8
#define NROWS (BATCH * N)   // 16384
#define CAPN 256            // shortlist capacity per row
#define T2 512              // DA kernel threads
#define RPT (N / T2)        // 4 rows per thread

typedef unsigned long long u64;
typedef unsigned u32;

#define DEADK 0xFFFFFFFFFFFFFFFFull

// ---------------- DPP wave64 reductions -----------------------------------
__device__ __forceinline__ unsigned wave_umin_bcast(unsigned x) {
#define DPP_MIN(ctrl)                                                          \
  {                                                                            \
    unsigned t = (unsigned)__builtin_amdgcn_update_dpp((int)x, (int)x, ctrl,   \
                                                       0xf, 0xf, false);       \
    x = t < x ? t : x;                                                         \
  }
  DPP_MIN(0x111) DPP_MIN(0x112) DPP_MIN(0x114) DPP_MIN(0x118)
  DPP_MIN(0x142) DPP_MIN(0x143)
#undef DPP_MIN
  return (unsigned)__builtin_amdgcn_readlane((int)x, 63);
}

__device__ __forceinline__ unsigned wave_umax_bcast(unsigned x) {
#define DPP_MAX(ctrl)                                                          \
  {                                                                            \
    unsigned t = (unsigned)__builtin_amdgcn_update_dpp((int)x, (int)x, ctrl,   \
                                                       0xf, 0xf, false);       \
    x = t > x ? t : x;                                                         \
  }
  DPP_MAX(0x111) DPP_MAX(0x112) DPP_MAX(0x114) DPP_MAX(0x118)
  DPP_MAX(0x142) DPP_MAX(0x143)
#undef DPP_MAX
  return (unsigned)__builtin_amdgcn_readlane((int)x, 63);
}

#define DPP64_MIN(x, ctrl)                                                     \
  {                                                                            \
    u32 lo_ = (u32)(x), hi_ = (u32)((x) >> 32);                                \
    u32 tlo_ = (u32)__builtin_amdgcn_update_dpp((int)lo_, (int)lo_, (ctrl),    \
                                                0xf, 0xf, false);              \
    u32 thi_ = (u32)__builtin_amdgcn_update_dpp((int)hi_, (int)hi_, (ctrl),    \
                                                0xf, 0xf, false);              \
    u64 t_ = ((u64)thi_ << 32) | tlo_;                                         \
    x = t_ < x ? t_ : x;                                                       \
  }

__device__ __forceinline__ u64 wave_min64_l63(u64 x) {
  DPP64_MIN(x, 0x111) DPP64_MIN(x, 0x112) DPP64_MIN(x, 0x114)
  DPP64_MIN(x, 0x118) DPP64_MIN(x, 0x142) DPP64_MIN(x, 0x143)
  return x;
}

// Exact-order distance: ((dx*dx + dy*dy) + dz*dz), no FMA contraction, sqrtf.
#define DIST(qx, qy, qz, TX, TY, TZ, j, dout)                                  \
  do {                                                                         \
    _Pragma("clang fp contract(off)")                                          \
    float dx_ = (qx) - (TX)[j];                                                \
    float dy_ = (qy) - (TY)[j];                                                \
    float dz_ = (qz) - (TZ)[j];                                                \
    float s_ = dx_ * dx_ + dy_ * dy_ + dz_ * dz_;                              \
    dout = sqrtf(s_);                                                          \
  } while (0)

// ---------------- Phase 1a: tau-shortlist (proven R2-R8) -------------------
// Shortlist = COMPLETE set {key : d <= tau}, prefix-closed under (d,j) order.
__global__ __launch_bounds__(256, 1)
void emd_shortlist_kernel(const float* __restrict__ pred,
                          const float* __restrict__ target,
                          u64* __restrict__ keys,
                          u32* __restrict__ cnts) {
    __shared__ float tx[N], ty[N], tz[N];
    const int b  = blockIdx.x >> 9;
    const int r0 = (blockIdx.x & 511) << 2;
    const float* tb = target + (size_t)b * N * 3;

    for (int idx = threadIdx.x; idx < 3 * N; idx += 256) {
        float v = tb[idx];
        int n = idx / 3, c = idx - 3 * n;
        if (c == 0) tx[n] = v; else if (c == 1) ty[n] = v; else tz[n] = v;
    }
    __syncthreads();

    const int wid = threadIdx.x >> 6, lane = threadIdx.x & 63;
    const int i = r0 + wid;
    const size_t row = (size_t)b * N + i;
    const float* pb = pred + row * 3;
    const float qx = pb[0], qy = pb[1], qz = pb[2];

    float d[32];
    float m = 3.4e38f;
    #pragma unroll
    for (int c = 0; c < 32; ++c) {
        const int j = (c << 6) + lane;
        float dd;
        DIST(qx, qy, qz, tx, ty, tz, j, dd);
        d[c] = dd;
        m = fminf(m, dd);
    }

    unsigned mb = __float_as_uint(m);
    {   // pair-min (xor1 quad_perm): tau = max of 32 min-of-64 -> E[cnt]~130
        unsigned t = (unsigned)__builtin_amdgcn_update_dpp((int)mb, (int)mb,
                                                           0x0B1, 0xf, 0xf, false);
        mb = t < mb ? t : mb;
    }
    const unsigned tau = wave_umax_bcast(mb);
    const float tauf = __uint_as_float(tau);

    u64* krow = keys + row * (size_t)CAPN;
    unsigned base = 0;
    #pragma unroll
    for (int c = 0; c < 32; ++c) {
        const bool p = d[c] <= tauf;
        const u64 bm = __ballot(p);
        if (p) {
            unsigned off = base + (unsigned)__popcll(bm & ((1ull << lane) - 1ull));
            if (off < (unsigned)CAPN)
                krow[off] = ((u64)__float_as_uint(d[c]) << 32) |
                            (unsigned)((c << 6) + lane);
        }
        base += (unsigned)__popcll(bm);
    }
    if (lane == 0) cnts[row] = base;
}

// ---------------- Phase 1b: in-place sorted top-64 extraction --------------
#define CSWAP(a, b)                                                            \
  { u64 mn_ = (a) < (b) ? (a) : (b); u64 mx_ = (a) < (b) ? (b) : (a);          \
    (a) = mn_; (b) = mx_; }

__global__ __launch_bounds__(256, 1)
void emd_sort64_kernel(u64* __restrict__ keys, const u32* __restrict__ cnts) {
    const int wid = threadIdx.x >> 6, lane = threadIdx.x & 63;
    const size_t row = (size_t)blockIdx.x * 4 + wid;
    u64* krow = keys + row * (size_t)CAPN;

    const u32 cnt = cnts[row];
    const u32 lim = (cnt > (u32)CAPN) ? 0u : cnt;   // overflow -> no candidates

    u64 k0 = ((u32)lane       < lim) ? krow[lane      ] : DEADK;
    u64 k1 = ((u32)lane + 64  < lim) ? krow[lane + 64 ] : DEADK;
    u64 k2 = ((u32)lane + 128 < lim) ? krow[lane + 128] : DEADK;
    u64 k3 = ((u32)lane + 192 < lim) ? krow[lane + 192] : DEADK;

    CSWAP(k0, k1) CSWAP(k2, k3) CSWAP(k0, k2) CSWAP(k1, k3) CSWAP(k1, k2)

    u64 mykey = DEADK;
    for (int it = 0; it < 64; ++it) {
        u64 wm = wave_min64_l63(k0);
        u32 wlo = (u32)__builtin_amdgcn_readlane((int)(u32)wm, 63);
        u32 whi = (u32)__builtin_amdgcn_readlane((int)(u32)(wm >> 32), 63);
        if (whi == 0xFFFFFFFFu) break;            // all exhausted (cnt < 64)
        const u64 wkey = ((u64)whi << 32) | wlo;
        mykey = (lane == it) ? wkey : mykey;      // capture in lane `it`
        const bool eq = (k0 == wkey);             // unique (distinct j)
        k0 = eq ? k1 : k0; k1 = eq ? k2 : k1; k2 = eq ? k3 : k2;
        k3 = eq ? DEADK : k3;
    }
    krow[lane] = mykey;   // in-place: all reads consumed above
}

// ---------------- Phase 2: parallel deferred acceptance --------------------
// THEORY: greedy nearest-unused in row order == serial dictatorship. With
// target preference = lowest row index, the stable matching is UNIQUE and
// equals the greedy outcome (induction: any stable matching gives row 0 its
// top pick, then row 1 its top pick among the rest, ...). Row-proposing
// deferred acceptance converges to it under ANY proposal order (McVitie-
// Wilson), so it parallelizes: holder[t] = atomicMin over proposing rows
// (monotone decreasing => rejections are permanent), displaced rows advance
// down their exact sorted top-64 preference list (phase 1b); rows that
// exhaust the list continue their exact preference order by scanning all
// targets with holder > r (never-rejecting targets). Fixpoint (no displaced
// rows) == unique stable matching == reference output. 512 threads, 4 rows
// each; 8 waves of TLP finally hide LDS/atomic latency.
__global__ __launch_bounds__(T2, 1)
void emd_da_kernel(const float* __restrict__ pred,
                   const float* __restrict__ target,
                   const u64* __restrict__ keys,
                   float* __restrict__ batch_emd) {
    __shared__ u32 holder[N];
    __shared__ float tx[N], ty[N], tz[N];
    __shared__ u32 nunm;
    __shared__ double dsum[T2];

    const int tid = threadIdx.x;
    const int b = blockIdx.x;
    const float* pb = pred + (size_t)b * N * 3;
    const float* tb = target + (size_t)b * N * 3;
    const u64* kb = keys + (size_t)b * N * (size_t)CAPN;
    volatile u32* vh = holder;

    for (int idx = tid; idx < 3 * N; idx += T2) {
        float vt = tb[idx];
        int n = idx / 3, c = idx - 3 * n;
        if (c == 0) tx[n] = vt; else if (c == 1) ty[n] = vt; else tz[n] = vt;
    }
    for (int j = tid; j < N; j += T2) holder[j] = 0xFFFFFFFFu;
    __syncthreads();

    u32 cur[RPT], curd[RPT], pos[RPT];
    #pragma unroll
    for (int k = 0; k < RPT; ++k) { cur[k] = 0xFFFFFFFFu; curd[k] = 0; pos[k] = 0; }

    for (int pass = 0; pass < 8192; ++pass) {
        // ---- verify + (re)propose my rows ----
        #pragma unroll
        for (int k = 0; k < RPT; ++k) {
            const u32 r = (u32)(tid * RPT + k);
            bool unm;
            if (cur[k] == 0xFFFFFFFFu) {
                unm = true;                       // first pass
            } else if (vh[cur[k]] == r) {
                unm = false;                      // still holding
            } else {
                unm = true;                       // displaced: rejection is permanent
                if (pos[k] < 64) pos[k]++;
            }
            if (!unm) continue;

            for (;;) {
                if (pos[k] < 64) {
                    const u64 key = kb[(size_t)r * CAPN + pos[k]];
                    if ((u32)(key >> 32) == 0xFFFFFFFFu) { pos[k] = 64; continue; }
                    const u32 t = (u32)key & (N - 1);
                    if (vh[t] < r) { pos[k]++; continue; }      // pre-reject
                    const u32 old = atomicMin(&holder[t], r);
                    if (old < r) { pos[k]++; continue; }        // rejected
                    cur[k] = t; curd[k] = (u32)(key >> 32);     // tentatively held
                    break;
                } else {
                    // exact preference continuation: best target that never
                    // rejected r (holder monotone => holder[j] > r <=> never)
                    const float qx = pb[3 * r], qy = pb[3 * r + 1],
                                qz = pb[3 * r + 2];
                    u64 best = DEADK;
                    for (int j = 0; j < N; ++j) {
                        if (vh[j] > r) {
                            float dd;
                            DIST(qx, qy, qz, tx, ty, tz, j, dd);
                            const u64 kk = ((u64)__float_as_uint(dd) << 32) |
                                           (u32)j;
                            best = kk < best ? kk : best;
                        }
                    }
                    const u32 t = (u32)best & (N - 1);
                    const u32 old = atomicMin(&holder[t], r);
                    if (old < r) continue;                      // raced: rescan
                    cur[k] = t; curd[k] = (u32)(best >> 32);
                    break;
                }
            }
        }
        // ---- convergence check (consistent snapshot after barrier) ----
        __syncthreads();
        if (tid == 0) nunm = 0;
        __syncthreads();
        u32 loose = 0;
        #pragma unroll
        for (int k = 0; k < RPT; ++k)
            loose += (vh[cur[k]] != (u32)(tid * RPT + k)) ? 1u : 0u;
        if (loose) atomicAdd(&nunm, loose);
        __syncthreads();
        if (nunm == 0) break;
    }

    double s = 0.0;
    #pragma unroll
    for (int k = 0; k < RPT; ++k) s += (double)__uint_as_float(curd[k]);
    dsum[tid] = s;
    __syncthreads();
    if (tid == 0) {
        double tot = 0.0;
        for (int t = 0; t < T2; ++t) tot += dsum[t];
        batch_emd[b] = (float)(tot / N);
    }
}

// ---------------- exact full-scan helper (tiny-ws fallback kernel) --------
__device__ __forceinline__ u64 full_scan_row(
    int lane, float qx, float qy, float qz,
    const float* tx, const float* ty, const float* tz,
    const unsigned char* used) {
  u32 dl = 0xFFFFFFFFu, jl = 0u;
  #pragma unroll 8
  for (int c = 0; c < 32; ++c) {
    const int j = (c << 6) + lane;
    if (!used[j]) {
      float dd;
      DIST(qx, qy, qz, tx, ty, tz, j, dd);
      const u32 db = __float_as_uint(dd);
      if (db < dl) { dl = db; jl = (u32)j; }
    }
  }
  const u32 dmin = wave_umin_bcast(dl);
  const u32 jc = (dl == dmin) ? jl : 0xFFFFFFFFu;
  const u32 jmin = wave_umin_bcast(jc);
  return ((u64)dmin << 32) | jmin;
}

__global__ __launch_bounds__(64, 1)
void emd_greedy_full_kernel(const float* __restrict__ pred,
                            const float* __restrict__ target,
                            float* __restrict__ batch_emd) {
    __shared__ float tx[N], ty[N], tz[N];
    __shared__ float qxs[N], qys[N], qzs[N];
    __shared__ unsigned char used[N];

    const int lane = threadIdx.x;
    const int b = blockIdx.x;
    const float* pb = pred + (size_t)b * N * 3;
    const float* tb = target + (size_t)b * N * 3;

    for (int idx = lane; idx < 3 * N; idx += 64) {
        float vp = pb[idx], vt = tb[idx];
        int n = idx / 3, c = idx - 3 * n;
        if (c == 0)      { qxs[n] = vp; tx[n] = vt; }
        else if (c == 1) { qys[n] = vp; ty[n] = vt; }
        else             { qzs[n] = vp; tz[n] = vt; }
    }
    for (int j = lane; j < N; j += 64) used[j] = 0;

    double sum = 0.0;
    for (int i = 0; i < N; ++i) {
        u64 fs = full_scan_row(lane, qxs[i], qys[i], qzs[i], tx, ty, tz, used);
        sum += (double)__uint_as_float((u32)(fs >> 32));
        if (lane == 0) used[(u32)fs] = 1;
    }
    if (lane == 0) batch_emd[b] = (float)(sum / N);
}

__global__ void emd_mean_kernel(const float* __restrict__ batch_emd,
                                float* __restrict__ out) {
    double s = 0.0;
    for (int b = 0; b < BATCH; ++b) s += (double)batch_emd[b];
    out[0] = (float)(s / BATCH);
}

extern "C" void kernel_launch(void* const* d_in, const int* in_sizes, int n_in,
                              void* d_out, int out_size, void* d_ws, size_t ws_size,
                              hipStream_t stream) {
    const float* pred   = (const float*)d_in[0];
    const float* target = (const float*)d_in[1];
    float* out = (float*)d_out;
    char* wsb = (char*)d_ws;

    const size_t keysz = (size_t)NROWS * CAPN * 8;   // 33.6 MB
    const size_t cntsz = (size_t)NROWS * 4;

    if (ws_size >= keysz + cntsz + 32) {
        u64* keys = (u64*)wsb;
        u32* cnts = (u32*)(wsb + keysz);
        float* emd = (float*)(wsb + keysz + cntsz);
        emd_shortlist_kernel<<<NROWS / 4, 256, 0, stream>>>(pred, target, keys, cnts);
        emd_sort64_kernel<<<NROWS / 4, 256, 0, stream>>>(keys, cnts);
        emd_da_kernel<<<BATCH, T2, 0, stream>>>(pred, target, keys, emd);
        emd_mean_kernel<<<1, 1, 0, stream>>>(emd, out);
    } else {
        float* emd = (float*)wsb;
        emd_greedy_full_kernel<<<BATCH, 64, 0, stream>>>(pred, target, emd);
        emd_mean_kernel<<<1, 1, 0, stream>>>(emd, out);
    }
}

// Round 10
// 3030.464 us; speedup vs baseline: 12.7262x; 12.7262x over previous
//
#include <hip/hip_runtime.h>
#include <stdint.h>

#define N 2048
#define BATCH 8
#define NROWS (BATCH * N)   // 16384
#define CAPN 256            // shortlist capacity per row

typedef unsigned long long u64;
typedef unsigned u32;

#define DEADK 0xFFFFFFFFFFFFFFFFull

// ---------------- DPP wave64 reductions -----------------------------------
__device__ __forceinline__ unsigned wave_umin_bcast(unsigned x) {
#define DPP_MIN(ctrl)                                                          \
  {                                                                            \
    unsigned t = (unsigned)__builtin_amdgcn_update_dpp((int)x, (int)x, ctrl,   \
                                                       0xf, 0xf, false);       \
    x = t < x ? t : x;                                                         \
  }
  DPP_MIN(0x111) DPP_MIN(0x112) DPP_MIN(0x114) DPP_MIN(0x118)
  DPP_MIN(0x142) DPP_MIN(0x143)
#undef DPP_MIN
  return (unsigned)__builtin_amdgcn_readlane((int)x, 63);
}

__device__ __forceinline__ unsigned wave_umax_bcast(unsigned x) {
#define DPP_MAX(ctrl)                                                          \
  {                                                                            \
    unsigned t = (unsigned)__builtin_amdgcn_update_dpp((int)x, (int)x, ctrl,   \
                                                       0xf, 0xf, false);       \
    x = t > x ? t : x;                                                         \
  }
  DPP_MAX(0x111) DPP_MAX(0x112) DPP_MAX(0x114) DPP_MAX(0x118)
  DPP_MAX(0x142) DPP_MAX(0x143)
#undef DPP_MAX
  return (unsigned)__builtin_amdgcn_readlane((int)x, 63);
}

#define DPP64_MIN(x, ctrl)                                                     \
  {                                                                            \
    u32 lo_ = (u32)(x), hi_ = (u32)((x) >> 32);                                \
    u32 tlo_ = (u32)__builtin_amdgcn_update_dpp((int)lo_, (int)lo_, (ctrl),    \
                                                0xf, 0xf, false);              \
    u32 thi_ = (u32)__builtin_amdgcn_update_dpp((int)hi_, (int)hi_, (ctrl),    \
                                                0xf, 0xf, false);              \
    u64 t_ = ((u64)thi_ << 32) | tlo_;                                         \
    x = t_ < x ? t_ : x;                                                       \
  }

__device__ __forceinline__ u64 wave_min64_l63(u64 x) {
  DPP64_MIN(x, 0x111) DPP64_MIN(x, 0x112) DPP64_MIN(x, 0x114)
  DPP64_MIN(x, 0x118) DPP64_MIN(x, 0x142) DPP64_MIN(x, 0x143)
  return x;
}

// Exact-order distance: ((dx*dx + dy*dy) + dz*dz), no FMA contraction, sqrtf.
#define DIST(qx, qy, qz, TX, TY, TZ, j, dout)                                  \
  do {                                                                         \
    _Pragma("clang fp contract(off)")                                          \
    float dx_ = (qx) - (TX)[j];                                                \
    float dy_ = (qy) - (TY)[j];                                                \
    float dz_ = (qz) - (TZ)[j];                                                \
    float s_ = dx_ * dx_ + dy_ * dy_ + dz_ * dz_;                              \
    dout = sqrtf(s_);                                                          \
  } while (0)

// ---------------- Phase 1a: tau-shortlist (proven R2-R9) -------------------
// Shortlist = COMPLETE set {key : d <= tau}, prefix-closed under (d,j) order.
__global__ __launch_bounds__(256, 1)
void emd_shortlist_kernel(const float* __restrict__ pred,
                          const float* __restrict__ target,
                          u64* __restrict__ keys,
                          u32* __restrict__ cnts) {
    __shared__ float tx[N], ty[N], tz[N];
    const int b  = blockIdx.x >> 9;
    const int r0 = (blockIdx.x & 511) << 2;
    const float* tb = target + (size_t)b * N * 3;

    for (int idx = threadIdx.x; idx < 3 * N; idx += 256) {
        float v = tb[idx];
        int n = idx / 3, c = idx - 3 * n;
        if (c == 0) tx[n] = v; else if (c == 1) ty[n] = v; else tz[n] = v;
    }
    __syncthreads();

    const int wid = threadIdx.x >> 6, lane = threadIdx.x & 63;
    const int i = r0 + wid;
    const size_t row = (size_t)b * N + i;
    const float* pb = pred + row * 3;
    const float qx = pb[0], qy = pb[1], qz = pb[2];

    float d[32];
    float m = 3.4e38f;
    #pragma unroll
    for (int c = 0; c < 32; ++c) {
        const int j = (c << 6) + lane;
        float dd;
        DIST(qx, qy, qz, tx, ty, tz, j, dd);
        d[c] = dd;
        m = fminf(m, dd);
    }

    unsigned mb = __float_as_uint(m);
    {   // pair-min (xor1 quad_perm): tau = max of 32 min-of-64 -> E[cnt]~130
        unsigned t = (unsigned)__builtin_amdgcn_update_dpp((int)mb, (int)mb,
                                                           0x0B1, 0xf, 0xf, false);
        mb = t < mb ? t : mb;
    }
    const unsigned tau = wave_umax_bcast(mb);
    const float tauf = __uint_as_float(tau);

    u64* krow = keys + row * (size_t)CAPN;
    unsigned base = 0;
    #pragma unroll
    for (int c = 0; c < 32; ++c) {
        const bool p = d[c] <= tauf;
        const u64 bm = __ballot(p);
        if (p) {
            unsigned off = base + (unsigned)__popcll(bm & ((1ull << lane) - 1ull));
            if (off < (unsigned)CAPN)
                krow[off] = ((u64)__float_as_uint(d[c]) << 32) |
                            (unsigned)((c << 6) + lane);
        }
        base += (unsigned)__popcll(bm);
    }
    if (lane == 0) cnts[row] = base;
}

// ---------------- Phase 1b: in-place sorted top-64 extraction --------------
#define CSWAP(a, b)                                                            \
  { u64 mn_ = (a) < (b) ? (a) : (b); u64 mx_ = (a) < (b) ? (b) : (a);          \
    (a) = mn_; (b) = mx_; }

__global__ __launch_bounds__(256, 1)
void emd_sort64_kernel(u64* __restrict__ keys, const u32* __restrict__ cnts) {
    const int wid = threadIdx.x >> 6, lane = threadIdx.x & 63;
    const size_t row = (size_t)blockIdx.x * 4 + wid;
    u64* krow = keys + row * (size_t)CAPN;

    const u32 cnt = cnts[row];
    const u32 lim = (cnt > (u32)CAPN) ? 0u : cnt;   // overflow -> no candidates

    u64 k0 = ((u32)lane       < lim) ? krow[lane      ] : DEADK;
    u64 k1 = ((u32)lane + 64  < lim) ? krow[lane + 64 ] : DEADK;
    u64 k2 = ((u32)lane + 128 < lim) ? krow[lane + 128] : DEADK;
    u64 k3 = ((u32)lane + 192 < lim) ? krow[lane + 192] : DEADK;

    CSWAP(k0, k1) CSWAP(k2, k3) CSWAP(k0, k2) CSWAP(k1, k3) CSWAP(k1, k2)

    u64 mykey = DEADK;
    for (int it = 0; it < 64; ++it) {
        u64 wm = wave_min64_l63(k0);
        u32 wlo = (u32)__builtin_amdgcn_readlane((int)(u32)wm, 63);
        u32 whi = (u32)__builtin_amdgcn_readlane((int)(u32)(wm >> 32), 63);
        if (whi == 0xFFFFFFFFu) break;            // all exhausted (cnt < 64)
        const u64 wkey = ((u64)whi << 32) | wlo;
        mykey = (lane == it) ? wkey : mykey;      // capture in lane `it`
        const bool eq = (k0 == wkey);             // unique (distinct j)
        k0 = eq ? k1 : k0; k1 = eq ? k2 : k1; k2 = eq ? k3 : k2;
        k3 = eq ? DEADK : k3;
    }
    krow[lane] = mykey;   // in-place: all reads consumed above
}

// ---------------- Phase 2: single-wave work-queue deferred acceptance ------
// THEOREM (HW-validated in R9, absmax 0.0): greedy row-order matching ==
// unique stable matching (targets prefer lowest row index) == row-proposing
// DA under ANY proposal order. holder[] updated by atomicMin is monotone =>
// rejections permanent. This kernel runs DA asynchronously in ONE wave:
// 64 lanes pop rows from a queue; each iteration a busy lane consumes its
// pref entry (global load issued LAST iteration -> pipelined), does one LDS
// atomicMin; on displacement the lane ADOPTS the displaced row immediately
// (chains advance 1 hop/iteration, 64 chains concurrently). Rows exhausting
// their sorted top-64 (exact prefix of the prefix-closed tau-set) continue
// their exact preference order via wave-cooperative scans over holder[j]>r.
__global__ __launch_bounds__(64, 1)
void emd_da_queue_kernel(const float* __restrict__ pred,
                         const float* __restrict__ target,
                         const u64* __restrict__ keys,
                         float* __restrict__ batch_emd) {
    __shared__ float tx[N], ty[N], tz[N];        // 24KB
    __shared__ u32 holder[N];                    // 8KB: min proposing row
    __shared__ u32 dmatch[N];                    // 8KB: d-bits of row's hold
    __shared__ unsigned short posn[N];           // 4KB: next pref index
    __shared__ u32 queue[N];                     // 8KB ring
    __shared__ u32 exq[N];                       // 8KB exhausted ring
    __shared__ u32 qtail_s, extail_s;
    __shared__ double dsum[64];

    const int lane = threadIdx.x;
    const int b = blockIdx.x;
    const float* pb = pred + (size_t)b * N * 3;
    const float* tb = target + (size_t)b * N * 3;
    const u64* kb = keys + (size_t)b * N * (size_t)CAPN;

    for (int idx = lane; idx < 3 * N; idx += 64) {
        float vt = tb[idx];
        int n = idx / 3, c = idx - 3 * n;
        if (c == 0) tx[n] = vt; else if (c == 1) ty[n] = vt; else tz[n] = vt;
    }
    for (int j = lane; j < N; j += 64) {
        holder[j] = 0xFFFFFFFFu; dmatch[j] = 0; posn[j] = 0; queue[j] = (u32)j;
    }
    if (lane == 0) { qtail_s = N; extail_s = 0; }
    // single wave: LDS ops are program-ordered; no barriers needed

    u32 qhead = 0, exhead = 0;          // uniform across the wave
    u32 myrow = 0xFFFFFFFFu, myp = 0;
    u64 mykey = 0;

    for (int guard = 0; guard < 400000; ++guard) {
        // ---- phase 1: busy lanes consume the pref entry loaded last iter --
        if (myrow != 0xFFFFFFFFu) {
            const u32 dv = (u32)(mykey >> 32);
            const u32 t  = (u32)mykey & (N - 1);
            if (dv == 0xFFFFFFFFu) {                      // list exhausted
                posn[myrow] = 64;
                u32 ei = atomicAdd(&extail_s, 1);
                exq[ei & (N - 1)] = myrow;
                myrow = 0xFFFFFFFFu;
            } else {
                const u32 old = atomicMin(&holder[t], myrow);
                if (old < myrow) {                        // rejected
                    ++myp;
                    if (myp >= 64) {
                        posn[myrow] = 64;
                        u32 ei = atomicAdd(&extail_s, 1);
                        exq[ei & (N - 1)] = myrow;
                        myrow = 0xFFFFFFFFu;
                    } else {
                        mykey = kb[(size_t)myrow * CAPN + myp];  // next iter
                    }
                } else {                                  // tentatively held
                    dmatch[myrow] = dv;
                    posn[myrow] = (unsigned short)(myp + 1);
                    if (old != 0xFFFFFFFFu) {
                        // ADOPT the displaced row: chain continues in-lane
                        myrow = old;
                        myp = posn[old];
                        if (myp >= 64) {
                            u32 ei = atomicAdd(&extail_s, 1);
                            exq[ei & (N - 1)] = myrow;
                            myrow = 0xFFFFFFFFu;
                        } else {
                            mykey = kb[(size_t)myrow * CAPN + myp];
                        }
                    } else {
                        myrow = 0xFFFFFFFFu;
                    }
                }
            }
        }
        // ---- phase 2: idle lanes pop from the queue (wave-coordinated) ----
        const u32 qt = qtail_s;
        const bool idle = (myrow == 0xFFFFFFFFu);
        const u64 im = __ballot(idle);
        const u32 avail = qt - qhead;
        const u32 npop = (u32)__popcll(im);
        const u32 take = npop < avail ? npop : avail;
        if (idle) {
            const u32 rank = (u32)__popcll(im & ((1ull << lane) - 1ull));
            if (rank < take) {
                const u32 r = queue[(qhead + rank) & (N - 1)];
                const u32 p = posn[r];
                if (p >= 64) {
                    u32 ei = atomicAdd(&extail_s, 1);
                    exq[ei & (N - 1)] = r;
                } else {
                    myrow = r; myp = p;
                    mykey = kb[(size_t)r * CAPN + p];     // consumed next iter
                }
            }
        }
        qhead += take;
        // ---- termination / cooperative exhausted-row resolution ----------
        const u64 busy = __ballot(myrow != 0xFFFFFFFFu);
        if (busy == 0ull && qhead == qtail_s) {
            if (exhead == extail_s) break;                // converged
            const u32 r = exq[exhead & (N - 1)];
            ++exhead;
            // exact preference continuation: best target never rejecting r
            const float qx = pb[3 * r], qy = pb[3 * r + 1], qz = pb[3 * r + 2];
            u64 best = DEADK;
            #pragma unroll 4
            for (int c = 0; c < 32; ++c) {
                const int j = (c << 6) + lane;
                const u32 h = holder[j];
                float dd;
                DIST(qx, qy, qz, tx, ty, tz, j, dd);
                const u64 kk = ((u64)__float_as_uint(dd) << 32) | (u32)j;
                if (h > r && kk < best) best = kk;
            }
            const u64 wm = wave_min64_l63(best);
            const u32 wlo = (u32)__builtin_amdgcn_readlane((int)(u32)wm, 63);
            const u32 whi = (u32)__builtin_amdgcn_readlane((int)(u32)(wm >> 32), 63);
            if (lane == 0) {
                const u32 t2 = wlo & (N - 1);
                const u32 old = atomicMin(&holder[t2], r);  // old > r by scan
                dmatch[r] = whi;
                posn[r] = 64;
                if (old != 0xFFFFFFFFu) {
                    u32 qi = atomicAdd(&qtail_s, 1);
                    queue[qi & (N - 1)] = old;
                }
            }
        }
    }

    // final sum: every row matched; dmatch holds its final distance bits
    double s = 0.0;
    for (int k = 0; k < 32; ++k)
        s += (double)__uint_as_float(dmatch[(k << 6) + lane]);
    dsum[lane] = s;
    if (lane == 0) {
        double tot = 0.0;
        for (int t = 0; t < 64; ++t) tot += dsum[t];
        batch_emd[b] = (float)(tot / N);
    }
}

// ---------------- exact full-scan helper (tiny-ws fallback kernel) --------
__device__ __forceinline__ u64 full_scan_row(
    int lane, float qx, float qy, float qz,
    const float* tx, const float* ty, const float* tz,
    const unsigned char* used) {
  u32 dl = 0xFFFFFFFFu, jl = 0u;
  #pragma unroll 8
  for (int c = 0; c < 32; ++c) {
    const int j = (c << 6) + lane;
    if (!used[j]) {
      float dd;
      DIST(qx, qy, qz, tx, ty, tz, j, dd);
      const u32 db = __float_as_uint(dd);
      if (db < dl) { dl = db; jl = (u32)j; }
    }
  }
  const u32 dmin = wave_umin_bcast(dl);
  const u32 jc = (dl == dmin) ? jl : 0xFFFFFFFFu;
  const u32 jmin = wave_umin_bcast(jc);
  return ((u64)dmin << 32) | jmin;
}

__global__ __launch_bounds__(64, 1)
void emd_greedy_full_kernel(const float* __restrict__ pred,
                            const float* __restrict__ target,
                            float* __restrict__ batch_emd) {
    __shared__ float tx[N], ty[N], tz[N];
    __shared__ float qxs[N], qys[N], qzs[N];
    __shared__ unsigned char used[N];

    const int lane = threadIdx.x;
    const int b = blockIdx.x;
    const float* pb = pred + (size_t)b * N * 3;
    const float* tb = target + (size_t)b * N * 3;

    for (int idx = lane; idx < 3 * N; idx += 64) {
        float vp = pb[idx], vt = tb[idx];
        int n = idx / 3, c = idx - 3 * n;
        if (c == 0)      { qxs[n] = vp; tx[n] = vt; }
        else if (c == 1) { qys[n] = vp; ty[n] = vt; }
        else             { qzs[n] = vp; tz[n] = vt; }
    }
    for (int j = lane; j < N; j += 64) used[j] = 0;

    double sum = 0.0;
    for (int i = 0; i < N; ++i) {
        u64 fs = full_scan_row(lane, qxs[i], qys[i], qzs[i], tx, ty, tz, used);
        sum += (double)__uint_as_float((u32)(fs >> 32));
        if (lane == 0) used[(u32)fs] = 1;
    }
    if (lane == 0) batch_emd[b] = (float)(sum / N);
}

__global__ void emd_mean_kernel(const float* __restrict__ batch_emd,
                                float* __restrict__ out) {
    double s = 0.0;
    for (int b = 0; b < BATCH; ++b) s += (double)batch_emd[b];
    out[0] = (float)(s / BATCH);
}

extern "C" void kernel_launch(void* const* d_in, const int* in_sizes, int n_in,
                              void* d_out, int out_size, void* d_ws, size_t ws_size,
                              hipStream_t stream) {
    const float* pred   = (const float*)d_in[0];
    const float* target = (const float*)d_in[1];
    float* out = (float*)d_out;
    char* wsb = (char*)d_ws;

    const size_t keysz = (size_t)NROWS * CAPN * 8;   // 33.6 MB
    const size_t cntsz = (size_t)NROWS * 4;

    if (ws_size >= keysz + cntsz + 32) {
        u64* keys = (u64*)wsb;
        u32* cnts = (u32*)(wsb + keysz);
        float* emd = (float*)(wsb + keysz + cntsz);
        emd_shortlist_kernel<<<NROWS / 4, 256, 0, stream>>>(pred, target, keys, cnts);
        emd_sort64_kernel<<<NROWS / 4, 256, 0, stream>>>(keys, cnts);
        emd_da_queue_kernel<<<BATCH, 64, 0, stream>>>(pred, target, keys, emd);
        emd_mean_kernel<<<1, 1, 0, stream>>>(emd, out);
    } else {
        float* emd = (float*)wsb;
        emd_greedy_full_kernel<<<BATCH, 64, 0, stream>>>(pred, target, emd);
        emd_mean_kernel<<<1, 1, 0, stream>>>(emd, out);
    }
}

// Round 11
// 2381.557 us; speedup vs baseline: 16.1937x; 1.2725x over previous
//
#include <hip/hip_runtime.h>
#include <stdint.h>

#define N 2048
#define BATCH 8
#define NROWS (BATCH * N)   // 16384
#define CAPN 256            // shortlist capacity per row

typedef unsigned long long u64;
typedef unsigned u32;

#define DEADK 0xFFFFFFFFFFFFFFFFull

// ---------------- DPP wave64 reductions -----------------------------------
__device__ __forceinline__ unsigned wave_umin_bcast(unsigned x) {
#define DPP_MIN(ctrl)                                                          \
  {                                                                            \
    unsigned t = (unsigned)__builtin_amdgcn_update_dpp((int)x, (int)x, ctrl,   \
                                                       0xf, 0xf, false);       \
    x = t < x ? t : x;                                                         \
  }
  DPP_MIN(0x111) DPP_MIN(0x112) DPP_MIN(0x114) DPP_MIN(0x118)
  DPP_MIN(0x142) DPP_MIN(0x143)
#undef DPP_MIN
  return (unsigned)__builtin_amdgcn_readlane((int)x, 63);
}

__device__ __forceinline__ unsigned wave_umax_bcast(unsigned x) {
#define DPP_MAX(ctrl)                                                          \
  {                                                                            \
    unsigned t = (unsigned)__builtin_amdgcn_update_dpp((int)x, (int)x, ctrl,   \
                                                       0xf, 0xf, false);       \
    x = t > x ? t : x;                                                         \
  }
  DPP_MAX(0x111) DPP_MAX(0x112) DPP_MAX(0x114) DPP_MAX(0x118)
  DPP_MAX(0x142) DPP_MAX(0x143)
#undef DPP_MAX
  return (unsigned)__builtin_amdgcn_readlane((int)x, 63);
}

#define DPP64_MIN(x, ctrl)                                                     \
  {                                                                            \
    u32 lo_ = (u32)(x), hi_ = (u32)((x) >> 32);                                \
    u32 tlo_ = (u32)__builtin_amdgcn_update_dpp((int)lo_, (int)lo_, (ctrl),    \
                                                0xf, 0xf, false);              \
    u32 thi_ = (u32)__builtin_amdgcn_update_dpp((int)hi_, (int)hi_, (ctrl),    \
                                                0xf, 0xf, false);              \
    u64 t_ = ((u64)thi_ << 32) | tlo_;                                         \
    x = t_ < x ? t_ : x;                                                       \
  }

__device__ __forceinline__ u64 wave_min64_l63(u64 x) {
  DPP64_MIN(x, 0x111) DPP64_MIN(x, 0x112) DPP64_MIN(x, 0x114)
  DPP64_MIN(x, 0x118) DPP64_MIN(x, 0x142) DPP64_MIN(x, 0x143)
  return x;
}

// Exact-order distance: ((dx*dx + dy*dy) + dz*dz), no FMA contraction, sqrtf.
#define DIST(qx, qy, qz, TX, TY, TZ, j, dout)                                  \
  do {                                                                         \
    _Pragma("clang fp contract(off)")                                          \
    float dx_ = (qx) - (TX)[j];                                                \
    float dy_ = (qy) - (TY)[j];                                                \
    float dz_ = (qz) - (TZ)[j];                                                \
    float s_ = dx_ * dx_ + dy_ * dy_ + dz_ * dz_;                              \
    dout = sqrtf(s_);                                                          \
  } while (0)

// ---------------- Phase 1a: tau-shortlist (proven R2-R10) ------------------
// Shortlist = COMPLETE set {key : d <= tau}, prefix-closed under (d,j) order.
__global__ __launch_bounds__(256, 1)
void emd_shortlist_kernel(const float* __restrict__ pred,
                          const float* __restrict__ target,
                          u64* __restrict__ keys,
                          u32* __restrict__ cnts) {
    __shared__ float tx[N], ty[N], tz[N];
    const int b  = blockIdx.x >> 9;
    const int r0 = (blockIdx.x & 511) << 2;
    const float* tb = target + (size_t)b * N * 3;

    for (int idx = threadIdx.x; idx < 3 * N; idx += 256) {
        float v = tb[idx];
        int n = idx / 3, c = idx - 3 * n;
        if (c == 0) tx[n] = v; else if (c == 1) ty[n] = v; else tz[n] = v;
    }
    __syncthreads();

    const int wid = threadIdx.x >> 6, lane = threadIdx.x & 63;
    const int i = r0 + wid;
    const size_t row = (size_t)b * N + i;
    const float* pb = pred + row * 3;
    const float qx = pb[0], qy = pb[1], qz = pb[2];

    float d[32];
    float m = 3.4e38f;
    #pragma unroll
    for (int c = 0; c < 32; ++c) {
        const int j = (c << 6) + lane;
        float dd;
        DIST(qx, qy, qz, tx, ty, tz, j, dd);
        d[c] = dd;
        m = fminf(m, dd);
    }

    unsigned mb = __float_as_uint(m);
    {   // pair-min (xor1 quad_perm): tau = max of 32 min-of-64 -> E[cnt]~130
        unsigned t = (unsigned)__builtin_amdgcn_update_dpp((int)mb, (int)mb,
                                                           0x0B1, 0xf, 0xf, false);
        mb = t < mb ? t : mb;
    }
    const unsigned tau = wave_umax_bcast(mb);
    const float tauf = __uint_as_float(tau);

    u64* krow = keys + row * (size_t)CAPN;
    unsigned base = 0;
    #pragma unroll
    for (int c = 0; c < 32; ++c) {
        const bool p = d[c] <= tauf;
        const u64 bm = __ballot(p);
        if (p) {
            unsigned off = base + (unsigned)__popcll(bm & ((1ull << lane) - 1ull));
            if (off < (unsigned)CAPN)
                krow[off] = ((u64)__float_as_uint(d[c]) << 32) |
                            (unsigned)((c << 6) + lane);
        }
        base += (unsigned)__popcll(bm);
    }
    if (lane == 0) cnts[row] = base;
}

// ---------------- Phase 1b: in-place sorted top-64 extraction --------------
#define CSWAP(a, b)                                                            \
  { u64 mn_ = (a) < (b) ? (a) : (b); u64 mx_ = (a) < (b) ? (b) : (a);          \
    (a) = mn_; (b) = mx_; }

__global__ __launch_bounds__(256, 1)
void emd_sort64_kernel(u64* __restrict__ keys, const u32* __restrict__ cnts) {
    const int wid = threadIdx.x >> 6, lane = threadIdx.x & 63;
    const size_t row = (size_t)blockIdx.x * 4 + wid;
    u64* krow = keys + row * (size_t)CAPN;

    const u32 cnt = cnts[row];
    const u32 lim = (cnt > (u32)CAPN) ? 0u : cnt;   // overflow -> no candidates

    u64 k0 = ((u32)lane       < lim) ? krow[lane      ] : DEADK;
    u64 k1 = ((u32)lane + 64  < lim) ? krow[lane + 64 ] : DEADK;
    u64 k2 = ((u32)lane + 128 < lim) ? krow[lane + 128] : DEADK;
    u64 k3 = ((u32)lane + 192 < lim) ? krow[lane + 192] : DEADK;

    CSWAP(k0, k1) CSWAP(k2, k3) CSWAP(k0, k2) CSWAP(k1, k3) CSWAP(k1, k2)

    u64 mykey = DEADK;
    for (int it = 0; it < 64; ++it) {
        u64 wm = wave_min64_l63(k0);
        u32 wlo = (u32)__builtin_amdgcn_readlane((int)(u32)wm, 63);
        u32 whi = (u32)__builtin_amdgcn_readlane((int)(u32)(wm >> 32), 63);
        if (whi == 0xFFFFFFFFu) break;            // all exhausted (cnt < 64)
        const u64 wkey = ((u64)whi << 32) | wlo;
        mykey = (lane == it) ? wkey : mykey;      // capture in lane `it`
        const bool eq = (k0 == wkey);             // unique (distinct j)
        k0 = eq ? k1 : k0; k1 = eq ? k2 : k1; k2 = eq ? k3 : k2;
        k3 = eq ? DEADK : k3;
    }
    krow[lane] = mykey;   // in-place: all reads consumed above
}

// ---------------- Phase 2: DA with local termination (no polling) ----------
// THEOREM (HW-validated R9/R10, absmax 0.0): greedy row-order matching ==
// unique stable matching == row-proposing DA under ANY proposal order;
// holder[] via atomicMin is monotone => rejections permanent.
// Stage 1: 1024 threads, 2 rows each, walk-with-ADOPTION: a thread that
// displaces a held row immediately adopts and continues it, so every
// displacement is resolved by its displacer -> when all threads finish,
// stage-1 fixpoint holds; ONE barrier, no convergence polling (R10's bug
// class eliminated). Stale cross-wave posn reads only re-walk permanently-
// rejecting targets (safe). Stage 2: wave 0 drains the exhausted queue
// exactly (list-resume via ballot, else full scan over {j: holder[j]>r},
// nonempty since unmatched r has <=r rejecting targets); Sum(holder) strictly
// decreases per proposal => terminates. Final: sum d(holder[t],t) over targets.
__global__ __launch_bounds__(1024, 1)
void emd_da2_kernel(const float* __restrict__ pred,
                    const float* __restrict__ target,
                    const u64* __restrict__ keys,
                    float* __restrict__ batch_emd) {
    __shared__ float tx[N], ty[N], tz[N];        // 24KB targets
    __shared__ float px[N], py[N], pz[N];        // 24KB preds
    __shared__ u32 holder[N];                    // 8KB
    __shared__ unsigned short posn[N];           // 4KB
    __shared__ u32 exq[N];                       // 8KB ring
    __shared__ u32 extail;
    __shared__ double dsum[1024];

    const int tid = threadIdx.x;
    const int lane = tid & 63;
    const int b = blockIdx.x;
    const float* pb = pred + (size_t)b * N * 3;
    const float* tb = target + (size_t)b * N * 3;
    const u64* kb = keys + (size_t)b * N * (size_t)CAPN;

    for (int idx = tid; idx < 3 * N; idx += 1024) {
        float vp = pb[idx], vt = tb[idx];
        int n = idx / 3, c = idx - 3 * n;
        if (c == 0)      { px[n] = vp; tx[n] = vt; }
        else if (c == 1) { py[n] = vp; ty[n] = vt; }
        else             { pz[n] = vp; tz[n] = vt; }
    }
    for (int j = tid; j < N; j += 1024) { holder[j] = 0xFFFFFFFFu; posn[j] = 0; }
    if (tid == 0) extail = 0;
    __syncthreads();

    // ---- stage 1: per-thread walks with adoption ----
    #pragma unroll
    for (int k = 0; k < 2; ++k) {
        u32 r = (u32)tid + (k ? 1024u : 0u);
        u32 p = 0;
        for (int it = 0; it < 100000; ++it) {
            if (p >= 64) {
                posn[r] = 64;
                u32 ei = atomicAdd(&extail, 1u);
                exq[ei & (N - 1)] = r;
                break;
            }
            const u64 key = kb[(size_t)r * CAPN + p];
            const u32 dv = (u32)(key >> 32);
            if (dv == 0xFFFFFFFFu) {               // list ends early / overflow
                posn[r] = 64;
                u32 ei = atomicAdd(&extail, 1u);
                exq[ei & (N - 1)] = r;
                break;
            }
            const u32 t = (u32)key & (N - 1);
            if (holder[t] < r) { ++p; continue; }  // pre-reject (stale-safe)
            const u32 old = atomicMin(&holder[t], r);
            if (old < r) { ++p; continue; }        // rejected
            posn[r] = (unsigned short)(p + 1);     // held
            if (old == 0xFFFFFFFFu) break;         // empty target: chain done
            r = old; p = posn[r];                  // ADOPT displaced row
        }
    }
    __syncthreads();

    // ---- stage 2: wave 0 drains exhausted/displaced rows exactly ----
    if (tid < 64) {
        u32 head = 0;
        for (int it = 0; it < 200000; ++it) {
            if (head >= atomicAdd(&extail, 0u)) break;   // fresh read
            const u32 r = exq[head & (N - 1)]; ++head;
            const u32 p = posn[r];
            u32 jw = 0, dw = 0;
            bool got = false;
            if (p < 64) {
                // resume list: 64 entries, first with holder > r (pref order)
                const u64 key = kb[(size_t)r * CAPN + lane];
                const u32 dv = (u32)(key >> 32);
                const u32 t = (u32)key & (N - 1);
                const bool cand = ((u32)lane >= p) && (dv != 0xFFFFFFFFu) &&
                                  (holder[t] > r);
                const u64 bal = __ballot(cand);
                if (bal) {
                    const int L = __ffsll((long long)bal) - 1;
                    jw = (u32)__builtin_amdgcn_readlane((int)t, L);
                    dw = (u32)__builtin_amdgcn_readlane((int)dv, L);
                    if (lane == 0) posn[r] = (unsigned short)(L + 1);
                    got = true;
                } else if (lane == 0) {
                    posn[r] = 64;
                }
            }
            if (!got) {
                // full scan: min (d,j) over {j : holder[j] > r} (nonempty)
                const float qx = px[r], qy = py[r], qz = pz[r];
                u64 best = DEADK;
                #pragma unroll 4
                for (int c = 0; c < 32; ++c) {
                    const int j = (c << 6) + lane;
                    float dd;
                    DIST(qx, qy, qz, tx, ty, tz, j, dd);
                    const u64 kk = ((u64)__float_as_uint(dd) << 32) | (u32)j;
                    if (holder[j] > r && kk < best) best = kk;
                }
                const u64 wm = wave_min64_l63(best);
                jw = (u32)__builtin_amdgcn_readlane((int)(u32)wm, 63) & (N - 1);
                dw = (u32)__builtin_amdgcn_readlane((int)(u32)(wm >> 32), 63);
            }
            if (lane == 0) {
                const u32 old = atomicMin(&holder[jw], r);  // old > r by check
                if (old != 0xFFFFFFFFu) {                   // displaced: requeue
                    u32 ei = atomicAdd(&extail, 1u);
                    exq[ei & (N - 1)] = old;
                }
            }
        }
    }
    __syncthreads();

    // ---- final sum over targets (recomputed DIST == key d, bit-identical) --
    double s = 0.0;
    #pragma unroll
    for (int k = 0; k < 2; ++k) {
        const int t = tid + (k ? 1024 : 0);
        const u32 r = holder[t] & (N - 1);
        float dd;
        DIST(px[r], py[r], pz[r], tx, ty, tz, t, dd);
        s += (double)dd;
    }
    dsum[tid] = s;
    __syncthreads();
    for (int st = 512; st >= 1; st >>= 1) {
        if (tid < st) dsum[tid] += dsum[tid + st];
        __syncthreads();
    }
    if (tid == 0) batch_emd[b] = (float)(dsum[0] / N);
}

// ---------------- exact full-scan helper (tiny-ws fallback kernel) --------
__device__ __forceinline__ u64 full_scan_row(
    int lane, float qx, float qy, float qz,
    const float* tx, const float* ty, const float* tz,
    const unsigned char* used) {
  u32 dl = 0xFFFFFFFFu, jl = 0u;
  #pragma unroll 8
  for (int c = 0; c < 32; ++c) {
    const int j = (c << 6) + lane;
    if (!used[j]) {
      float dd;
      DIST(qx, qy, qz, tx, ty, tz, j, dd);
      const u32 db = __float_as_uint(dd);
      if (db < dl) { dl = db; jl = (u32)j; }
    }
  }
  const u32 dmin = wave_umin_bcast(dl);
  const u32 jc = (dl == dmin) ? jl : 0xFFFFFFFFu;
  const u32 jmin = wave_umin_bcast(jc);
  return ((u64)dmin << 32) | jmin;
}

__global__ __launch_bounds__(64, 1)
void emd_greedy_full_kernel(const float* __restrict__ pred,
                            const float* __restrict__ target,
                            float* __restrict__ batch_emd) {
    __shared__ float tx[N], ty[N], tz[N];
    __shared__ float qxs[N], qys[N], qzs[N];
    __shared__ unsigned char used[N];

    const int lane = threadIdx.x;
    const int b = blockIdx.x;
    const float* pb = pred + (size_t)b * N * 3;
    const float* tb = target + (size_t)b * N * 3;

    for (int idx = lane; idx < 3 * N; idx += 64) {
        float vp = pb[idx], vt = tb[idx];
        int n = idx / 3, c = idx - 3 * n;
        if (c == 0)      { qxs[n] = vp; tx[n] = vt; }
        else if (c == 1) { qys[n] = vp; ty[n] = vt; }
        else             { qzs[n] = vp; tz[n] = vt; }
    }
    for (int j = lane; j < N; j += 64) used[j] = 0;

    double sum = 0.0;
    for (int i = 0; i < N; ++i) {
        u64 fs = full_scan_row(lane, qxs[i], qys[i], qzs[i], tx, ty, tz, used);
        sum += (double)__uint_as_float((u32)(fs >> 32));
        if (lane == 0) used[(u32)fs] = 1;
    }
    if (lane == 0) batch_emd[b] = (float)(sum / N);
}

__global__ void emd_mean_kernel(const float* __restrict__ batch_emd,
                                float* __restrict__ out) {
    double s = 0.0;
    for (int b = 0; b < BATCH; ++b) s += (double)batch_emd[b];
    out[0] = (float)(s / BATCH);
}

extern "C" void kernel_launch(void* const* d_in, const int* in_sizes, int n_in,
                              void* d_out, int out_size, void* d_ws, size_t ws_size,
                              hipStream_t stream) {
    const float* pred   = (const float*)d_in[0];
    const float* target = (const float*)d_in[1];
    float* out = (float*)d_out;
    char* wsb = (char*)d_ws;

    const size_t keysz = (size_t)NROWS * CAPN * 8;   // 33.6 MB
    const size_t cntsz = (size_t)NROWS * 4;

    if (ws_size >= keysz + cntsz + 32) {
        u64* keys = (u64*)wsb;
        u32* cnts = (u32*)(wsb + keysz);
        float* emd = (float*)(wsb + keysz + cntsz);
        emd_shortlist_kernel<<<NROWS / 4, 256, 0, stream>>>(pred, target, keys, cnts);
        emd_sort64_kernel<<<NROWS / 4, 256, 0, stream>>>(keys, cnts);
        emd_da2_kernel<<<BATCH, 1024, 0, stream>>>(pred, target, keys, emd);
        emd_mean_kernel<<<1, 1, 0, stream>>>(emd, out);
    } else {
        float* emd = (float*)wsb;
        emd_greedy_full_kernel<<<BATCH, 64, 0, stream>>>(pred, target, emd);
        emd_mean_kernel<<<1, 1, 0, stream>>>(emd, out);
    }
}

// Round 12
// 560.489 us; speedup vs baseline: 68.8080x; 4.2491x over previous
//
#include <hip/hip_runtime.h>
#include <stdint.h>

#define N 2048
#define BATCH 8
#define NROWS (BATCH * N)   // 16384
#define CAPN 256            // shortlist capacity per row
#define EXQ 2048            // event ring size
#define INV 0xFFFFFFFFu

typedef unsigned long long u64;
typedef unsigned u32;

#define DEADK 0xFFFFFFFFFFFFFFFFull

// ---------------- DPP wave64 reductions -----------------------------------
__device__ __forceinline__ unsigned wave_umin_bcast(unsigned x) {
#define DPP_MIN(ctrl)                                                          \
  {                                                                            \
    unsigned t = (unsigned)__builtin_amdgcn_update_dpp((int)x, (int)x, ctrl,   \
                                                       0xf, 0xf, false);       \
    x = t < x ? t : x;                                                         \
  }
  DPP_MIN(0x111) DPP_MIN(0x112) DPP_MIN(0x114) DPP_MIN(0x118)
  DPP_MIN(0x142) DPP_MIN(0x143)
#undef DPP_MIN
  return (unsigned)__builtin_amdgcn_readlane((int)x, 63);
}

__device__ __forceinline__ unsigned wave_umax_bcast(unsigned x) {
#define DPP_MAX(ctrl)                                                          \
  {                                                                            \
    unsigned t = (unsigned)__builtin_amdgcn_update_dpp((int)x, (int)x, ctrl,   \
                                                       0xf, 0xf, false);       \
    x = t > x ? t : x;                                                         \
  }
  DPP_MAX(0x111) DPP_MAX(0x112) DPP_MAX(0x114) DPP_MAX(0x118)
  DPP_MAX(0x142) DPP_MAX(0x143)
#undef DPP_MAX
  return (unsigned)__builtin_amdgcn_readlane((int)x, 63);
}

#define DPP64_MIN(x, ctrl)                                                     \
  {                                                                            \
    u32 lo_ = (u32)(x), hi_ = (u32)((x) >> 32);                                \
    u32 tlo_ = (u32)__builtin_amdgcn_update_dpp((int)lo_, (int)lo_, (ctrl),    \
                                                0xf, 0xf, false);              \
    u32 thi_ = (u32)__builtin_amdgcn_update_dpp((int)hi_, (int)hi_, (ctrl),    \
                                                0xf, 0xf, false);              \
    u64 t_ = ((u64)thi_ << 32) | tlo_;                                         \
    x = t_ < x ? t_ : x;                                                       \
  }

__device__ __forceinline__ u64 wave_min64_l63(u64 x) {
  DPP64_MIN(x, 0x111) DPP64_MIN(x, 0x112) DPP64_MIN(x, 0x114)
  DPP64_MIN(x, 0x118) DPP64_MIN(x, 0x142) DPP64_MIN(x, 0x143)
  return x;
}

// Exact-order distance: ((dx*dx + dy*dy) + dz*dz), no FMA contraction, sqrtf.
#define DIST(qx, qy, qz, TX, TY, TZ, j, dout)                                  \
  do {                                                                         \
    _Pragma("clang fp contract(off)")                                          \
    float dx_ = (qx) - (TX)[j];                                                \
    float dy_ = (qy) - (TY)[j];                                                \
    float dz_ = (qz) - (TZ)[j];                                                \
    float s_ = dx_ * dx_ + dy_ * dy_ + dz_ * dz_;                              \
    dout = sqrtf(s_);                                                          \
  } while (0)

// ---------------- Phase 1a: tau-shortlist (proven R2-R11) ------------------
__global__ __launch_bounds__(256, 1)
void emd_shortlist_kernel(const float* __restrict__ pred,
                          const float* __restrict__ target,
                          u64* __restrict__ keys,
                          u32* __restrict__ cnts) {
    __shared__ float tx[N], ty[N], tz[N];
    const int b  = blockIdx.x >> 9;
    const int r0 = (blockIdx.x & 511) << 2;
    const float* tb = target + (size_t)b * N * 3;

    for (int idx = threadIdx.x; idx < 3 * N; idx += 256) {
        float v = tb[idx];
        int n = idx / 3, c = idx - 3 * n;
        if (c == 0) tx[n] = v; else if (c == 1) ty[n] = v; else tz[n] = v;
    }
    __syncthreads();

    const int wid = threadIdx.x >> 6, lane = threadIdx.x & 63;
    const int i = r0 + wid;
    const size_t row = (size_t)b * N + i;
    const float* pb = pred + row * 3;
    const float qx = pb[0], qy = pb[1], qz = pb[2];

    float d[32];
    float m = 3.4e38f;
    #pragma unroll
    for (int c = 0; c < 32; ++c) {
        const int j = (c << 6) + lane;
        float dd;
        DIST(qx, qy, qz, tx, ty, tz, j, dd);
        d[c] = dd;
        m = fminf(m, dd);
    }

    unsigned mb = __float_as_uint(m);
    {   // pair-min (xor1 quad_perm): tau = max of 32 min-of-64 -> E[cnt]~130
        unsigned t = (unsigned)__builtin_amdgcn_update_dpp((int)mb, (int)mb,
                                                           0x0B1, 0xf, 0xf, false);
        mb = t < mb ? t : mb;
    }
    const unsigned tau = wave_umax_bcast(mb);
    const float tauf = __uint_as_float(tau);

    u64* krow = keys + row * (size_t)CAPN;
    unsigned base = 0;
    #pragma unroll
    for (int c = 0; c < 32; ++c) {
        const bool p = d[c] <= tauf;
        const u64 bm = __ballot(p);
        if (p) {
            unsigned off = base + (unsigned)__popcll(bm & ((1ull << lane) - 1ull));
            if (off < (unsigned)CAPN)
                krow[off] = ((u64)__float_as_uint(d[c]) << 32) |
                            (unsigned)((c << 6) + lane);
        }
        base += (unsigned)__popcll(bm);
    }
    if (lane == 0) cnts[row] = base;
}

// ---------------- Phase 1b: in-place sorted top-64 extraction --------------
#define CSWAP(a, b)                                                            \
  { u64 mn_ = (a) < (b) ? (a) : (b); u64 mx_ = (a) < (b) ? (b) : (a);          \
    (a) = mn_; (b) = mx_; }

__global__ __launch_bounds__(256, 1)
void emd_sort64_kernel(u64* __restrict__ keys, const u32* __restrict__ cnts) {
    const int wid = threadIdx.x >> 6, lane = threadIdx.x & 63;
    const size_t row = (size_t)blockIdx.x * 4 + wid;
    u64* krow = keys + row * (size_t)CAPN;

    const u32 cnt = cnts[row];
    const u32 lim = (cnt > (u32)CAPN) ? 0u : cnt;   // overflow -> no candidates

    u64 k0 = ((u32)lane       < lim) ? krow[lane      ] : DEADK;
    u64 k1 = ((u32)lane + 64  < lim) ? krow[lane + 64 ] : DEADK;
    u64 k2 = ((u32)lane + 128 < lim) ? krow[lane + 128] : DEADK;
    u64 k3 = ((u32)lane + 192 < lim) ? krow[lane + 192] : DEADK;

    CSWAP(k0, k1) CSWAP(k2, k3) CSWAP(k0, k2) CSWAP(k1, k3) CSWAP(k1, k2)

    u64 mykey = DEADK;
    for (int it = 0; it < 64; ++it) {
        u64 wm = wave_min64_l63(k0);
        u32 wlo = (u32)__builtin_amdgcn_readlane((int)(u32)wm, 63);
        u32 whi = (u32)__builtin_amdgcn_readlane((int)(u32)(wm >> 32), 63);
        if (whi == 0xFFFFFFFFu) break;            // all exhausted (cnt < 64)
        const u64 wkey = ((u64)whi << 32) | wlo;
        mykey = (lane == it) ? wkey : mykey;      // capture in lane `it`
        const bool eq = (k0 == wkey);             // unique (distinct j)
        k0 = eq ? k1 : k0; k1 = eq ? k2 : k1; k2 = eq ? k3 : k2;
        k3 = eq ? DEADK : k3;
    }
    krow[lane] = mykey;   // in-place: all reads consumed above
}

// ---------------- Phase 2: DA, parallel stage 2 (all-LDS events) -----------
// THEOREM (HW-validated R9-R11, absmax 0.0): greedy row-order matching ==
// unique stable matching == row-proposing DA under ANY proposal order;
// holder[] via atomicMin monotone => rejections permanent; proposing to the
// best target in {j: holder[j] > r} == DA with doomed-proposal skipping.
// Stage 1: 2048 walks with adoption; keys read in 8-entry register segments
// (one 64B load per ~8 proposals). Stage 2: displacement/exhaustion events in
// an LDS ring drained by ALL 16 waves; each event resolved by a PURE-LDS full
// scan (no global loads -> no serial memory latency; R11's 2ms bug).
// Termination: claim i=atomicAdd(head); item ready when slot != INV; exit when
// done==talloc (read done FIRST, then talloc: done(t1)==talloc(t2), t1<t2,
// done monotone, done<=talloc => talloc(t2)==done(t2): quiesced, no producer
// in flight can exist). Races: stale holder reads only over-include (monotone)
// and are re-checked by atomicMin; loser rescans (set only shrinks).
__global__ __launch_bounds__(1024, 1)
void emd_da3_kernel(const float* __restrict__ pred,
                    const float* __restrict__ target,
                    const u64* __restrict__ keys,
                    float* __restrict__ batch_emd) {
    __shared__ float tx[N], ty[N], tz[N];        // 24KB targets
    __shared__ float px[N], py[N], pz[N];        // 24KB preds
    __shared__ u32 holder[N];                    // 8KB
    __shared__ unsigned short posn[N];           // 4KB
    __shared__ u32 exq[EXQ];                     // 8KB event ring
    __shared__ u32 talloc, done, head;
    __shared__ double dsum[1024];

    const int tid = threadIdx.x;
    const int lane = tid & 63;
    const int b = blockIdx.x;
    const float* pb = pred + (size_t)b * N * 3;
    const float* tb = target + (size_t)b * N * 3;
    const u64* kb = keys + (size_t)b * N * (size_t)CAPN;

    for (int idx = tid; idx < 3 * N; idx += 1024) {
        float vp = pb[idx], vt = tb[idx];
        int n = idx / 3, c = idx - 3 * n;
        if (c == 0)      { px[n] = vp; tx[n] = vt; }
        else if (c == 1) { py[n] = vp; ty[n] = vt; }
        else             { pz[n] = vp; tz[n] = vt; }
    }
    for (int j = tid; j < N; j += 1024) { holder[j] = INV; posn[j] = 0; }
    for (int j = tid; j < EXQ; j += 1024) exq[j] = INV;
    if (tid == 0) { talloc = 0; done = 0; head = 0; }
    __syncthreads();

    // ---- stage 1: walks with adoption; keys in 8-entry register segments --
    #pragma unroll
    for (int k = 0; k < 2; ++k) {
        u32 r = (u32)tid + (k ? 1024u : 0u);
        u32 p = 0;
        for (int guard = 0; guard < 100000; ++guard) {
            if (p >= 64) {   // exhausted -> event (pre-barrier plain write ok)
                const u32 s = atomicAdd(&talloc, 1u);
                exq[s & (EXQ - 1)] = r;
                break;
            }
            const u32 seg = p & ~7u;
            const u64* sp = kb + (size_t)r * CAPN + seg;
            const ulonglong2 q0 = *(const ulonglong2*)(sp + 0);
            const ulonglong2 q1 = *(const ulonglong2*)(sp + 2);
            const ulonglong2 q2 = *(const ulonglong2*)(sp + 4);
            const ulonglong2 q3 = *(const ulonglong2*)(sp + 6);
            const u64 kk0 = q0.x, kk1 = q0.y, kk2 = q1.x, kk3 = q1.y,
                      kk4 = q2.x, kk5 = q2.y, kk6 = q3.x, kk7 = q3.y;
            const int pin = (int)(p - seg);
            int st = 0;          // 0 walk, 2 chain done, 3 adopt, 4 exhausted
            u32 nr = 0;
#define S1STEP(KK, E)                                                          \
            if (st == 0 && (E) >= pin) {                                       \
                const u32 dv_ = (u32)((KK) >> 32);                             \
                if (dv_ == INV) { st = 4; }                                    \
                else {                                                         \
                    const u32 t_ = (u32)(KK) & (N - 1);                        \
                    if (holder[t_] > r) {                                      \
                        const u32 old_ = atomicMin(&holder[t_], r);            \
                        if (old_ > r) {                                        \
                            posn[r] = (unsigned short)(seg + (E) + 1);         \
                            if (old_ == INV) st = 2;                           \
                            else { nr = old_; st = 3; }                        \
                        }                                                      \
                    }                                                          \
                }                                                              \
            }
            S1STEP(kk0, 0) S1STEP(kk1, 1) S1STEP(kk2, 2) S1STEP(kk3, 3)
            S1STEP(kk4, 4) S1STEP(kk5, 5) S1STEP(kk6, 6) S1STEP(kk7, 7)
#undef S1STEP
            if (st == 0) { p = seg + 8; continue; }
            if (st == 2) break;
            if (st == 3) { r = nr; p = posn[nr]; continue; }
            // st == 4: list ended -> event
            {
                const u32 s = atomicAdd(&talloc, 1u);
                exq[s & (EXQ - 1)] = r;
                break;
            }
        }
    }
    __syncthreads();

    // ---- stage 2: all 16 waves drain the event ring (pure-LDS resolve) ----
    for (int guard = 0; guard < 100000; ++guard) {
        u32 i = 0;
        if (lane == 0) i = atomicAdd(&head, 1u);
        i = (u32)__shfl((int)i, 0, 64);
        u32 rrow = INV;
        for (int spin = 0; spin < 1000000; ++spin) {
            u32 v = 0, dn = 0, ta = 0;
            if (lane == 0) {
                v  = atomicOr(&exq[i & (EXQ - 1)], 0u);
                dn = atomicOr(&done, 0u);       // read done FIRST
                ta = atomicOr(&talloc, 0u);     // then talloc
            }
            v  = (u32)__shfl((int)v, 0, 64);
            dn = (u32)__shfl((int)dn, 0, 64);
            ta = (u32)__shfl((int)ta, 0, 64);
            if (v != INV && i < ta) {
                rrow = v;
                if (lane == 0) atomicExch(&exq[i & (EXQ - 1)], INV);
                break;
            }
            if (dn == ta && i >= ta) break;     // quiesced: nothing more comes
            __builtin_amdgcn_s_sleep(1);
        }
        if (rrow == INV) break;                 // wave exits stage 2
        // resolve rrow: full scan over {j: holder[j] > rrow} (pure LDS)
        const float qx = px[rrow], qy = py[rrow], qz = pz[rrow];
        for (int rty = 0; rty < 100000; ++rty) {
            u64 best = DEADK;
            #pragma unroll 4
            for (int c = 0; c < 32; ++c) {
                const int j = (c << 6) + lane;
                float dd;
                DIST(qx, qy, qz, tx, ty, tz, j, dd);
                const u64 kk = ((u64)__float_as_uint(dd) << 32) | (u32)j;
                if (holder[j] > rrow && kk < best) best = kk;
            }
            const u64 wm = wave_min64_l63(best);
            const u32 jw = (u32)__builtin_amdgcn_readlane((int)(u32)wm, 63) & (N - 1);
            u32 old = 0;
            if (lane == 0) old = atomicMin(&holder[jw], rrow);
            old = (u32)__shfl((int)old, 0, 64);
            if (old < rrow) continue;           // lost race: set shrank, rescan
            if (old != INV) {                   // displaced -> push event
                if (lane == 0) {
                    const u32 s = atomicAdd(&talloc, 1u);
                    atomicExch(&exq[s & (EXQ - 1)], old);
                }
            }
            break;
        }
        if (lane == 0) atomicAdd(&done, 1u);
    }
    __syncthreads();

    // ---- final sum over targets (recomputed DIST bit-identical to keys) ---
    double s = 0.0;
    #pragma unroll
    for (int k = 0; k < 2; ++k) {
        const int t = tid + (k ? 1024 : 0);
        const u32 r = holder[t] & (N - 1);
        float dd;
        DIST(px[r], py[r], pz[r], tx, ty, tz, t, dd);
        s += (double)dd;
    }
    dsum[tid] = s;
    __syncthreads();
    for (int st = 512; st >= 1; st >>= 1) {
        if (tid < st) dsum[tid] += dsum[tid + st];
        __syncthreads();
    }
    if (tid == 0) batch_emd[b] = (float)(dsum[0] / N);
}

// ---------------- exact full-scan helper (tiny-ws fallback kernel) --------
__device__ __forceinline__ u64 full_scan_row(
    int lane, float qx, float qy, float qz,
    const float* tx, const float* ty, const float* tz,
    const unsigned char* used) {
  u32 dl = 0xFFFFFFFFu, jl = 0u;
  #pragma unroll 8
  for (int c = 0; c < 32; ++c) {
    const int j = (c << 6) + lane;
    if (!used[j]) {
      float dd;
      DIST(qx, qy, qz, tx, ty, tz, j, dd);
      const u32 db = __float_as_uint(dd);
      if (db < dl) { dl = db; jl = (u32)j; }
    }
  }
  const u32 dmin = wave_umin_bcast(dl);
  const u32 jc = (dl == dmin) ? jl : 0xFFFFFFFFu;
  const u32 jmin = wave_umin_bcast(jc);
  return ((u64)dmin << 32) | jmin;
}

__global__ __launch_bounds__(64, 1)
void emd_greedy_full_kernel(const float* __restrict__ pred,
                            const float* __restrict__ target,
                            float* __restrict__ batch_emd) {
    __shared__ float tx[N], ty[N], tz[N];
    __shared__ float qxs[N], qys[N], qzs[N];
    __shared__ unsigned char used[N];

    const int lane = threadIdx.x;
    const int b = blockIdx.x;
    const float* pb = pred + (size_t)b * N * 3;
    const float* tb = target + (size_t)b * N * 3;

    for (int idx = lane; idx < 3 * N; idx += 64) {
        float vp = pb[idx], vt = tb[idx];
        int n = idx / 3, c = idx - 3 * n;
        if (c == 0)      { qxs[n] = vp; tx[n] = vt; }
        else if (c == 1) { qys[n] = vp; ty[n] = vt; }
        else             { qzs[n] = vp; tz[n] = vt; }
    }
    for (int j = lane; j < N; j += 64) used[j] = 0;

    double sum = 0.0;
    for (int i = 0; i < N; ++i) {
        u64 fs = full_scan_row(lane, qxs[i], qys[i], qzs[i], tx, ty, tz, used);
        sum += (double)__uint_as_float((u32)(fs >> 32));
        if (lane == 0) used[(u32)fs] = 1;
    }
    if (lane == 0) batch_emd[b] = (float)(sum / N);
}

__global__ void emd_mean_kernel(const float* __restrict__ batch_emd,
                                float* __restrict__ out) {
    double s = 0.0;
    for (int b = 0; b < BATCH; ++b) s += (double)batch_emd[b];
    out[0] = (float)(s / BATCH);
}

extern "C" void kernel_launch(void* const* d_in, const int* in_sizes, int n_in,
                              void* d_out, int out_size, void* d_ws, size_t ws_size,
                              hipStream_t stream) {
    const float* pred   = (const float*)d_in[0];
    const float* target = (const float*)d_in[1];
    float* out = (float*)d_out;
    char* wsb = (char*)d_ws;

    const size_t keysz = (size_t)NROWS * CAPN * 8;   // 33.6 MB
    const size_t cntsz = (size_t)NROWS * 4;

    if (ws_size >= keysz + cntsz + 32) {
        u64* keys = (u64*)wsb;
        u32* cnts = (u32*)(wsb + keysz);
        float* emd = (float*)(wsb + keysz + cntsz);
        emd_shortlist_kernel<<<NROWS / 4, 256, 0, stream>>>(pred, target, keys, cnts);
        emd_sort64_kernel<<<NROWS / 4, 256, 0, stream>>>(keys, cnts);
        emd_da3_kernel<<<BATCH, 1024, 0, stream>>>(pred, target, keys, emd);
        emd_mean_kernel<<<1, 1, 0, stream>>>(emd, out);
    } else {
        float* emd = (float*)wsb;
        emd_greedy_full_kernel<<<BATCH, 64, 0, stream>>>(pred, target, emd);
        emd_mean_kernel<<<1, 1, 0, stream>>>(emd, out);
    }
}